// Round 9
// baseline (127.451 us; speedup 1.0000x reference)
//
#include <hip/hip_runtime.h>
#include <math.h>

typedef unsigned long long ull;

// Problem constants (from setup_inputs): B=64, G=4999, P=50
constexpr int Bc = 64;
constexpr int Gc = 4999;
constexpr int Pc = 50;

constexpr int RUN   = 512;           // elements per sorted run (one wave)
constexpr int NRUN  = 10;            // runs per row (10*512 = 5120 >= G)
constexpr int NPAD  = NRUN * RUN;
constexpr int EPT   = 8;             // sort elements per lane (16 VGPRs)
constexpr int LPW   = 79;            // genes per lane in es phase
constexpr ull PADKEY = 0xFFFFFFFFFFFFFFFFull;

__device__ __forceinline__ ull shfl_xor64(ull v, int lm) {
    int lo = __shfl_xor((int)(unsigned)(v & 0xFFFFFFFFull), lm, 64);
    int hi = __shfl_xor((int)(unsigned)(v >> 32), lm, 64);
    return ((ull)(unsigned)hi << 32) | (unsigned)lo;
}

// ---------------------------------------------------------------------------
// Kernel 1: fused sort + rank. Grid (5,64) x 1024 thr (16 waves).
//  - waves 0..9: wave w bitonic-sorts run w of sample b entirely in registers
//    (round-7 verified network; redundant across the 5 rg-blocks — registers
//    are cheap, and this removes the runs[] global round-trip) -> LDS.
//  - waves 10..15 (rg==0 blocks only): pack pbits[g] concurrently. pbits is
//    consumed only by the NEXT dispatch — no cross-block hazard.
//  - after one barrier: thread t ranks element rg*1024+t: rank = own-run pos
//    + 9 binary searches over the other runs (keys unique -> exact bijection
//    onto [0,G)). Writes wq[rank] (|v|^0.25 decoded from key) + sidx[rank].
// ---------------------------------------------------------------------------
__global__ __launch_bounds__(1024) void sort_rank(
    const float* __restrict__ expr, const float* __restrict__ pathway,
    ull* __restrict__ pbits, float* __restrict__ wqout,
    unsigned short* __restrict__ sidxout, int G)
{
    __shared__ ull runsLDS[NPAD];   // 40960 B
    const int rg = blockIdx.x, b = blockIdx.y;
    const int tid = threadIdx.x;
    const int lane = tid & 63;
    const int w = tid >> 6;              // wave id 0..15

    if (w < NRUN) {
        // ---- sort run w in registers (round-7 verified) ----
        const int base = lane * EPT;
        const float* row = expr + (size_t)b * G;
        ull v[EPT];
#pragma unroll
        for (int o = 0; o < EPT; ++o) {
            int i = w * RUN + base + o;
            if (i < G) {
                unsigned u = __float_as_uint(row[i]);
                unsigned m = (u >> 31) ? ~u : (u | 0x80000000u);  // monotone map
                v[o] = ((ull)(~m) << 32) | (unsigned)i;
            } else {
                v[o] = PADKEY;
            }
        }
#pragma unroll
        for (int kk = 2; kk <= RUN; kk <<= 1) {
#pragma unroll
            for (int j = kk >> 1; j >= EPT; j >>= 1) {
                const int lm = j >> 3;
                const bool takeMin = (((lane & lm) == 0) == ((base & kk) == 0));
#pragma unroll
                for (int o = 0; o < EPT; ++o) {
                    ull c = shfl_xor64(v[o], lm);
                    ull mn = (v[o] < c) ? v[o] : c;
                    ull mx = (v[o] < c) ? c : v[o];
                    v[o] = takeMin ? mn : mx;
                }
            }
#pragma unroll
            for (int j = 4; j >= 1; j >>= 1) {
                if (j < kk) {
#pragma unroll
                    for (int o = 0; o < EPT; ++o) {
                        if ((o & j) == 0) {
                            bool up = (((base + o) & kk) == 0);
                            ull a = v[o], c = v[o | j];
                            if ((a > c) == up) { v[o] = c; v[o | j] = a; }
                        }
                    }
                }
            }
        }
#pragma unroll
        for (int o = 0; o < EPT; ++o) runsLDS[w * RUN + base + o] = v[o];
    } else if (rg == 0) {
        // ---- pack pathway bits with the otherwise-idle waves ----
        // 64 blocks x 384 threads = 24576 >= G; consumed by next dispatch.
        for (int g = (w - NRUN) * 64 + lane; g < G; g += 6 * 64) {
            // only rg==0 exists here; g strides by 384 within this block,
            // blocks cover disjoint g via b offset:
        }
        int g = b * 384 + (w - NRUN) * 64 + lane;
        if (g < G) {
            ull m = 0;
#pragma unroll
            for (int p = 0; p < Pc; ++p)
                if (pathway[(size_t)p * G + g] > 0.0f) m |= (1ull << p);
            pbits[g] = m;
        }
    }
    __syncthreads();

    // ---- rank one element per thread ----
    const int e = rg * 1024 + tid;          // 0..5119
    const ull keyv = runsLDS[e];
    if (keyv == PADKEY) return;             // padding

    const int run = e >> 9;                 // e / 512
    int rank = e & 511;                     // own-run position (stable)
#pragma unroll
    for (int rr = 0; rr < NRUN; ++rr) {
        if (rr == run) continue;
        const ull* arr = &runsLDS[rr * RUN];
        int pos = 0;
#pragma unroll
        for (int s = RUN; s >= 1; s >>= 1) {
            int np = pos + s;
            if (np <= RUN && arr[np - 1] < keyv) pos = np;
        }
        rank += pos;                        // # elements < keyv
    }

    int idx = (int)(unsigned)(keyv & 0xFFFFFFFFu);
    unsigned m = ~((unsigned)(keyv >> 32));
    unsigned absbits = ((m >> 31) ? m : ~m) & 0x7FFFFFFFu;
    float av = __uint_as_float(absbits);
    wqout[(size_t)b * G + rank] = sqrtf(sqrtf(av));       // |v|^0.25
    sidxout[(size_t)b * G + rank] = (unsigned short)idx;
}

// ---------------------------------------------------------------------------
// Kernel 2: enrichment scores (round-8 verified scan). Grid (4,64) x 256:
// block (pg,b) handles pathways [pg*13, min(pg*13+13,P)). Staging gathers
// sm32[i] = (u32)(pbits[sidx[i]] >> pbeg) — 40 KB pbits table is L1/L2-hot.
// All LDS reads b32 at stride-79 (coprime with 32 banks -> conflict-free).
// ---------------------------------------------------------------------------
__global__ __launch_bounds__(256) void es_kernel(
    const float* __restrict__ wq, const unsigned short* __restrict__ sidx,
    const ull* __restrict__ pbits, float* __restrict__ out, int B, int P, int G)
{
    __shared__ float    swq[Gc];    // 19996 B
    __shared__ unsigned sm32[Gc];   // 19996 B  (~40 KB)

    const int pg = blockIdx.x;
    const int b  = blockIdx.y;
    const int tid = threadIdx.x;
    const int pbeg = pg * 13;
    const int pend = (pbeg + 13 < P) ? (pbeg + 13) : P;

    for (int i = tid; i < G; i += 256) {
        swq[i]  = wq[(size_t)b * G + i];
        sm32[i] = (unsigned)(pbits[sidx[(size_t)b * G + i]] >> pbeg);
    }
    __syncthreads();

    const int lane = tid & 63;
    const int w = tid >> 6;
    const int p0 = pbeg + w * 4;
    if (p0 >= pend) return;
    const int sh4 = w * 4;                 // shift within the u32 slice

    const int start = lane * LPW;
    const int cnt = (start + LPW < G) ? LPW : (G - start);

    // Pass A: per-chunk (sum w*hit, #hit) for 4 pathways at once
    double sw[4] = {0.0, 0.0, 0.0, 0.0};
    int sh[4] = {0, 0, 0, 0};
    for (int k = 0; k < cnt; ++k) {
        int s = start + k;
        unsigned nib = (sm32[s] >> sh4) & 15u;
        double wv = (double)swq[s];
#pragma unroll
        for (int q = 0; q < 4; ++q) {
            if ((nib >> q) & 1u) { sw[q] += wv; sh[q]++; }
        }
    }
    double norm[4], inv_denom[4], running[4];
    int sht[4];
#pragma unroll
    for (int q = 0; q < 4; ++q) {
        double swt = sw[q];
        int shq = sh[q];
#pragma unroll
        for (int off = 1; off < 64; off <<= 1) {
            swt += __shfl_xor(swt, off, 64);
            shq += __shfl_xor(shq, off, 64);
        }
        sht[q] = shq;
        norm[q]      = (swt > 0.0) ? 1.0 / swt : 1.0;
        inv_denom[q] = 1.0 / fmax((double)(G - shq), 1.0);
        double csum = sw[q] * norm[q] - (double)(cnt - sh[q]) * inv_denom[q];
        double x = csum;
#pragma unroll
        for (int off = 1; off < 64; off <<= 1) {
            double vv = __shfl_up(x, off, 64);
            if (lane >= off) x += vv;
        }
        running[q] = x - csum;     // exclusive prefix for this chunk
    }

    // Pass C: walk chunk, first-occurrence argmax of |running| (4 pathways)
    double bestv[4] = {-1.0, -1.0, -1.0, -1.0};
    double bestr[4] = {0.0, 0.0, 0.0, 0.0};
    int besti[4] = {0x7FFFFFFF, 0x7FFFFFFF, 0x7FFFFFFF, 0x7FFFFFFF};
    for (int k = 0; k < cnt; ++k) {
        int s = start + k;
        unsigned nib = (sm32[s] >> sh4) & 15u;
        double wv = (double)swq[s];
#pragma unroll
        for (int q = 0; q < 4; ++q) {
            running[q] += ((nib >> q) & 1u) ? wv * norm[q] : -inv_denom[q];
            double a = fabs(running[q]);
            if (a > bestv[q]) { bestv[q] = a; bestr[q] = running[q]; besti[q] = s; }
        }
    }
#pragma unroll
    for (int q = 0; q < 4; ++q) {
#pragma unroll
        for (int off = 1; off < 64; off <<= 1) {
            double ov  = __shfl_xor(bestv[q], off, 64);
            double orr = __shfl_xor(bestr[q], off, 64);
            int    oi  = __shfl_xor(besti[q], off, 64);
            if (ov > bestv[q] || (ov == bestv[q] && oi < besti[q])) {
                bestv[q] = ov; bestr[q] = orr; besti[q] = oi;
            }
        }
    }

    if (lane == 0) {
#pragma unroll
        for (int q = 0; q < 4; ++q) {
            int p = p0 + q;
            if (p < pend)
                out[(size_t)b * P + p] = (sht[q] > 0) ? (float)bestr[q] : 0.0f;
        }
    }
}

extern "C" void kernel_launch(void* const* d_in, const int* in_sizes, int n_in,
                              void* d_out, int out_size, void* d_ws, size_t ws_size,
                              hipStream_t stream) {
    const float* expr    = (const float*)d_in[0];   // [B, G]
    const float* pathway = (const float*)d_in[1];   // [P, G]
    float* out = (float*)d_out;                     // [B, P]

    // workspace layout (bytes):
    //   pbits ull[G]       @ 0        (40960 reserved)
    //   wq    f32[B*G]     @ 40960    (1279744 -> next 1320704)
    //   sidx  u16[B*G]     @ 1320704  (639872)    total ~2.0 MB
    char* ws = (char*)d_ws;
    ull*            pbits = (ull*)ws;
    float*          wqa   = (float*)(ws + 40960);
    unsigned short* sidx  = (unsigned short*)(ws + 1320704);

    sort_rank<<<dim3(5, Bc), dim3(1024), 0, stream>>>(
        expr, pathway, pbits, wqa, sidx, Gc);
    es_kernel<<<dim3(4, Bc), dim3(256), 0, stream>>>(
        wqa, sidx, pbits, out, Bc, Pc, Gc);
}

// Round 10
// 110.999 us; speedup vs baseline: 1.1482x; 1.1482x over previous
//
#include <hip/hip_runtime.h>
#include <math.h>

typedef unsigned long long ull;

// Problem constants (from setup_inputs): B=64, G=4999, P=50
constexpr int Bc = 64;
constexpr int Gc = 4999;
constexpr int Pc = 50;

constexpr int RUN   = 1024;          // elements per sorted run
constexpr int NRUN  = 5;             // runs per row (5*1024 = 5120 >= G)
constexpr int NPAD  = NRUN * RUN;
constexpr int LPW   = 79;            // genes per lane in es phase
constexpr ull PADKEY = 0xFFFFFFFFFFFFFFFFull;

__device__ __forceinline__ ull shfl_xor64(ull v, int lm) {
    int lo = __shfl_xor((int)(unsigned)(v & 0xFFFFFFFFull), lm, 64);
    int hi = __shfl_xor((int)(unsigned)(v >> 32), lm, 64);
    return ((ull)(unsigned)hi << 32) | (unsigned)lo;
}

// ---------------------------------------------------------------------------
// Kernel 1: sort one 1024-element chunk of one row (round-5 proven). 256 thr,
// 4 elems/thread. key = (~m)<<32 | idx (unique): ascending u64 == descending
// value, stable by index (== stable argsort(-x)). Register stages j<=2,
// wave-shuffle stages j=4..128, LDS stages j=256,512.
// Blocks with r==0 also pack pathway bits (consumed by next launch — safe).
// ---------------------------------------------------------------------------
__global__ __launch_bounds__(256) void chunk_sort(
    const float* __restrict__ expr, const float* __restrict__ pathway,
    ull* __restrict__ runs, ull* __restrict__ pbits, int P, int G)
{
    __shared__ ull key[RUN];
    const int r = blockIdx.x, b = blockIdx.y, tid = threadIdx.x;
    const int base = tid * 4;
    const float* row = expr + (size_t)b * G;

    ull v[4];
#pragma unroll
    for (int o = 0; o < 4; ++o) {
        int i = r * RUN + base + o;
        if (i < G) {
            unsigned u = __float_as_uint(row[i]);
            unsigned m = (u >> 31) ? ~u : (u | 0x80000000u);  // monotone map
            v[o] = ((ull)(~m) << 32) | (unsigned)i;
        } else {
            v[o] = PADKEY;
        }
    }

    for (int kk = 2; kk <= RUN; kk <<= 1) {
        const int j0 = kk >> 1;
        // LDS stages: j >= 256 (cross-wave)
        if (j0 >= 256) {
#pragma unroll
            for (int o = 0; o < 4; ++o) key[base + o] = v[o];
            __syncthreads();
            for (int j = j0; j >= 256; j >>= 1) {
#pragma unroll
                for (int t = tid; t < RUN / 2; t += 256) {
                    int i  = ((t & ~(j - 1)) << 1) | (t & (j - 1));
                    int ix = i | j;
                    ull a = key[i], c = key[ix];
                    bool up = ((i & kk) == 0);
                    if ((a > c) == up) { key[i] = c; key[ix] = a; }
                }
                __syncthreads();
            }
#pragma unroll
            for (int o = 0; o < 4; ++o) v[o] = key[base + o];
        }
        // wave-shuffle stages: j = min(j0,128) .. 4 (partner tid^(j/4), same wave)
        int jstart = (j0 > 128) ? 128 : j0;
        for (int j = jstart; j >= 4; j >>= 1) {
            int lm = j >> 2;
            bool takeMin = (((tid & lm) == 0) == ((base & kk) == 0));
#pragma unroll
            for (int o = 0; o < 4; ++o) {
                ull c = shfl_xor64(v[o], lm);
                ull mn = (v[o] < c) ? v[o] : c;
                ull mx = (v[o] < c) ? c : v[o];
                v[o] = takeMin ? mn : mx;
            }
        }
        // register stages: j = 2, 1
#pragma unroll
        for (int j = 2; j >= 1; j >>= 1) {
            if (j < kk) {
#pragma unroll
                for (int o = 0; o < 4; ++o) {
                    if ((o & j) == 0) {
                        bool up = (((base + o) & kk) == 0);
                        ull a = v[o], c = v[o | j];
                        if ((a > c) == up) { v[o] = c; v[o | j] = a; }
                    }
                }
            }
        }
    }

    ull* dst = runs + ((size_t)b * NRUN + r) * RUN;
#pragma unroll
    for (int o = 0; o < 4; ++o) dst[base + o] = v[o];

    // Folded pack: blocks with r==0 (64 blocks x 256 thr = 16384 >= G).
    if (r == 0) {
        int g = b * 256 + tid;
        if (g < G) {
            ull m = 0;
#pragma unroll
            for (int p = 0; p < Pc; ++p)
                if (pathway[(size_t)p * G + g] > 0.0f) m |= (1ull << p);
            pbits[g] = m;
        }
    }
}

// ---------------------------------------------------------------------------
// Kernel 2: rank + scatter, no duplication. Grid (5,64) x 1024: block (rg,b)
// stages all 5 runs (40 KB LDS) and ranks elements [rg*1024, rg*1024+1024),
// one per thread: rank = own-run pos + 4 binary searches (11 steps each; 4
// independent chains -> ILP). Keys unique -> exact bijection onto [0,G).
// Writes wq (|v|^0.25 decoded from key) + sidx (u16 gene index).
// ---------------------------------------------------------------------------
__global__ __launch_bounds__(1024) void rank_scatter(
    const ull* __restrict__ runs,
    float* __restrict__ wqout, unsigned short* __restrict__ sidxout, int G)
{
    __shared__ ull runsLDS[NPAD];   // 40960 B
    const int rg = blockIdx.x, b = blockIdx.y, tid = threadIdx.x;

    const ull* rowruns = runs + (size_t)b * NPAD;
    for (int i = tid; i < NPAD; i += 1024) runsLDS[i] = rowruns[i];
    __syncthreads();

    const int e = rg * 1024 + tid;          // 0..5119
    const ull keyv = runsLDS[e];
    if (keyv == PADKEY) return;             // padding

    const int run = e >> 10;                // e / 1024
    int rank = e & 1023;                    // own-run position (stable)
#pragma unroll
    for (int rr = 0; rr < NRUN; ++rr) {
        if (rr == run) continue;
        const ull* arr = &runsLDS[rr * RUN];
        int pos = 0;
#pragma unroll
        for (int s = RUN; s >= 1; s >>= 1) {
            int np = pos + s;
            if (np <= RUN && arr[np - 1] < keyv) pos = np;
        }
        rank += pos;                        // # elements < keyv
    }

    int idx = (int)(unsigned)(keyv & 0xFFFFFFFFu);
    unsigned m = ~((unsigned)(keyv >> 32));
    unsigned absbits = ((m >> 31) ? m : ~m) & 0x7FFFFFFFu;
    float av = __uint_as_float(absbits);
    wqout[(size_t)b * G + rank] = sqrtf(sqrtf(av));       // |v|^0.25
    sidxout[(size_t)b * G + rank] = (unsigned short)idx;
}

// ---------------------------------------------------------------------------
// Kernel 3: enrichment scores (round-8/9 verified scan). Grid (4,64) x 256:
// block (pg,b) handles pathways [pg*13, min(pg*13+13,P)). Staging gathers
// sm32[i] = (u32)(pbits[sidx[i]] >> pbeg) — 40 KB pbits table is L1/L2-hot.
// All LDS reads b32 at stride-79 (coprime with 32 banks -> conflict-free).
// Wave w computes 4 pathways in one pass over its 79-gene chunk.
// ---------------------------------------------------------------------------
__global__ __launch_bounds__(256) void es_kernel(
    const float* __restrict__ wq, const unsigned short* __restrict__ sidx,
    const ull* __restrict__ pbits, float* __restrict__ out, int B, int P, int G)
{
    __shared__ float    swq[Gc];    // 19996 B
    __shared__ unsigned sm32[Gc];   // 19996 B  (~40 KB)

    const int pg = blockIdx.x;
    const int b  = blockIdx.y;
    const int tid = threadIdx.x;
    const int pbeg = pg * 13;
    const int pend = (pbeg + 13 < P) ? (pbeg + 13) : P;

    for (int i = tid; i < G; i += 256) {
        swq[i]  = wq[(size_t)b * G + i];
        sm32[i] = (unsigned)(pbits[sidx[(size_t)b * G + i]] >> pbeg);
    }
    __syncthreads();

    const int lane = tid & 63;
    const int w = tid >> 6;
    const int p0 = pbeg + w * 4;
    if (p0 >= pend) return;
    const int sh4 = w * 4;                 // shift within the u32 slice

    const int start = lane * LPW;
    const int cnt = (start + LPW < G) ? LPW : (G - start);

    // Pass A: per-chunk (sum w*hit, #hit) for 4 pathways at once
    double sw[4] = {0.0, 0.0, 0.0, 0.0};
    int sh[4] = {0, 0, 0, 0};
    for (int k = 0; k < cnt; ++k) {
        int s = start + k;
        unsigned nib = (sm32[s] >> sh4) & 15u;
        double wv = (double)swq[s];
#pragma unroll
        for (int q = 0; q < 4; ++q) {
            if ((nib >> q) & 1u) { sw[q] += wv; sh[q]++; }
        }
    }
    double norm[4], inv_denom[4], running[4];
    int sht[4];
#pragma unroll
    for (int q = 0; q < 4; ++q) {
        double swt = sw[q];
        int shq = sh[q];
#pragma unroll
        for (int off = 1; off < 64; off <<= 1) {
            swt += __shfl_xor(swt, off, 64);
            shq += __shfl_xor(shq, off, 64);
        }
        sht[q] = shq;
        norm[q]      = (swt > 0.0) ? 1.0 / swt : 1.0;
        inv_denom[q] = 1.0 / fmax((double)(G - shq), 1.0);
        double csum = sw[q] * norm[q] - (double)(cnt - sh[q]) * inv_denom[q];
        double x = csum;
#pragma unroll
        for (int off = 1; off < 64; off <<= 1) {
            double vv = __shfl_up(x, off, 64);
            if (lane >= off) x += vv;
        }
        running[q] = x - csum;     // exclusive prefix for this chunk
    }

    // Pass C: walk chunk, first-occurrence argmax of |running| (4 pathways)
    double bestv[4] = {-1.0, -1.0, -1.0, -1.0};
    double bestr[4] = {0.0, 0.0, 0.0, 0.0};
    int besti[4] = {0x7FFFFFFF, 0x7FFFFFFF, 0x7FFFFFFF, 0x7FFFFFFF};
    for (int k = 0; k < cnt; ++k) {
        int s = start + k;
        unsigned nib = (sm32[s] >> sh4) & 15u;
        double wv = (double)swq[s];
#pragma unroll
        for (int q = 0; q < 4; ++q) {
            running[q] += ((nib >> q) & 1u) ? wv * norm[q] : -inv_denom[q];
            double a = fabs(running[q]);
            if (a > bestv[q]) { bestv[q] = a; bestr[q] = running[q]; besti[q] = s; }
        }
    }
#pragma unroll
    for (int q = 0; q < 4; ++q) {
#pragma unroll
        for (int off = 1; off < 64; off <<= 1) {
            double ov  = __shfl_xor(bestv[q], off, 64);
            double orr = __shfl_xor(bestr[q], off, 64);
            int    oi  = __shfl_xor(besti[q], off, 64);
            if (ov > bestv[q] || (ov == bestv[q] && oi < besti[q])) {
                bestv[q] = ov; bestr[q] = orr; besti[q] = oi;
            }
        }
    }

    if (lane == 0) {
#pragma unroll
        for (int q = 0; q < 4; ++q) {
            int p = p0 + q;
            if (p < pend)
                out[(size_t)b * P + p] = (sht[q] > 0) ? (float)bestr[q] : 0.0f;
        }
    }
}

extern "C" void kernel_launch(void* const* d_in, const int* in_sizes, int n_in,
                              void* d_out, int out_size, void* d_ws, size_t ws_size,
                              hipStream_t stream) {
    const float* expr    = (const float*)d_in[0];   // [B, G]
    const float* pathway = (const float*)d_in[1];   // [P, G]
    float* out = (float*)d_out;                     // [B, P]

    // workspace layout (bytes):
    //   pbits ull[G]        @ 0        (40960 reserved)
    //   runs  ull[B*NPAD]   @ 40960    (2621440)
    //   wq    f32[B*G]      @ 2662400  (1279744 -> next 3942144)
    //   sidx  u16[B*G]      @ 3942144  (639872)    total ~4.6 MB
    char* ws = (char*)d_ws;
    ull*            pbits = (ull*)ws;
    ull*            runs  = (ull*)(ws + 40960);
    float*          wqa   = (float*)(ws + 2662400);
    unsigned short* sidx  = (unsigned short*)(ws + 3942144);

    chunk_sort<<<dim3(NRUN, Bc), dim3(256), 0, stream>>>(
        expr, pathway, runs, pbits, Pc, Gc);
    rank_scatter<<<dim3(NRUN, Bc), dim3(1024), 0, stream>>>(runs, wqa, sidx, Gc);
    es_kernel<<<dim3(4, Bc), dim3(256), 0, stream>>>(
        wqa, sidx, pbits, out, Bc, Pc, Gc);
}